// Round 24
// baseline (223.033 us; speedup 1.0000x reference)
//
#include <hip/hip_runtime.h>
#include <hip/hip_fp16.h>
#include <math.h>

#define HID 128

typedef _Float16 half8 __attribute__((ext_vector_type(8)));
typedef float floatx4 __attribute__((ext_vector_type(4)));

// 8-byte packed 4x fp16
struct h4pack { __half2 a, b; };

__device__ __forceinline__ float4 h4tof4(h4pack h) {
  float2 lo = __half22float2(h.a);
  float2 hi = __half22float2(h.b);
  return make_float4(lo.x, lo.y, hi.x, hi.y);
}

__device__ __forceinline__ h4pack f4toh4(float4 v) {
  h4pack h;
  h.a = __floats2half2_rn(v.x, v.y);
  h.b = __floats2half2_rn(v.z, v.w);
  return h;
}

// ---------------- zero workspace --------------------------------------------
__global__ __launch_bounds__(256) void zero_kernel(int4* __restrict__ p, int n4) {
  int i = blockIdx.x * 256 + threadIdx.x;
  if (i < n4) p[i] = make_int4(0, 0, 0, 0);
}

// ---------------- CSR build (padded to 8-edge octets) ------------------------
__global__ __launch_bounds__(256) void hist_kernel(
    const int* __restrict__ dst, int* __restrict__ counts,
    int* __restrict__ rank, int E) {
  int e = blockIdx.x * 256 + threadIdx.x;
  if (e < E) rank[e] = atomicAdd(&counts[dst[e]], 1);
}

__global__ __launch_bounds__(256) void partial_kernel(
    const int* __restrict__ counts, int* __restrict__ partials, int N) {
  __shared__ int s[256];
  int idx = blockIdx.x * 256 + threadIdx.x;
  int c = (idx < N) ? counts[idx] : 0;
  s[threadIdx.x] = (idx < N) ? ((c + 7) & ~7) : 0;
  __syncthreads();
  for (int o = 128; o > 0; o >>= 1) {
    if (threadIdx.x < o) s[threadIdx.x] += s[threadIdx.x + o];
    __syncthreads();
  }
  if (threadIdx.x == 0) partials[blockIdx.x] = s[0];
}

__global__ __launch_bounds__(256) void scan2_kernel(
    const int* __restrict__ partials, int* __restrict__ bases, int NB) {
  __shared__ int s[256];
  int t = threadIdx.x;
  int v0 = (t < NB) ? partials[t] : 0;
  s[t] = v0;
  __syncthreads();
  for (int o = 1; o < 256; o <<= 1) {
    int v = (t >= o) ? s[t - o] : 0;
    __syncthreads();
    s[t] += v;
    __syncthreads();
  }
  bases[t] = s[t] - v0;   // exclusive
}

// offs + pad-fill (pads -> node 0; nulled in gat via true-count masking)
__global__ __launch_bounds__(256) void offs_kernel(
    const int* __restrict__ counts, const int* __restrict__ bases,
    int* __restrict__ offs, int* __restrict__ csr, int N) {
  __shared__ int s[256];
  int t = threadIdx.x;
  int idx = blockIdx.x * 256 + t;
  int deg = (idx < N) ? counts[idx] : 0;
  int c = (idx < N) ? ((deg + 7) & ~7) : 0;
  s[t] = c;
  __syncthreads();
  for (int o = 1; o < 256; o <<= 1) {
    int v = (t >= o) ? s[t - o] : 0;
    __syncthreads();
    s[t] += v;
    __syncthreads();
  }
  int base = bases[blockIdx.x];
  if (idx < N) {
    int o = base + s[t] - c;
    offs[idx] = o;
    for (int k = deg; k < c; ++k) csr[o + k] = 0;
  }
  if (idx == N - 1) offs[N] = base + s[t];
}

__global__ __launch_bounds__(256) void scatter_kernel(
    const int* __restrict__ src, const int* __restrict__ dst,
    const int* __restrict__ offs, const int* __restrict__ rank,
    int* __restrict__ csr, int E) {
  int e = blockIdx.x * 256 + threadIdx.x;
  if (e >= E) return;
  csr[offs[dst[e]] + rank[e]] = src[e];
}

// ---------------- W prep: both layers in one dispatch -----------------------
__global__ __launch_bounds__(256) void wprep2_kernel(
    const float* __restrict__ W1, const float* __restrict__ W2,
    __half* __restrict__ Wt1, __half* __restrict__ Wt2) {
  int b = blockIdx.x;
  const float* W = (b < 64) ? W1 : W2;
  __half* Wt = (b < 64) ? Wt1 : Wt2;
  int t = (b & 63) * 256 + threadIdx.x;   // 0..16383
  int k = t >> 7, c = t & 127;
  Wt[(size_t)c * HID + k] = __float2half(W[t]);
}

// ---------------- GEMM via MFMA: F[N,128](fp16) = A @ W ---------------------
__device__ __forceinline__ half8 embed8(const float* __restrict__ kp,
                                        const float* __restrict__ vp, int off) {
  float4 k0 = *(const float4*)(kp + off);
  float4 k1 = *(const float4*)(kp + off + 4);
  float4 v0 = *(const float4*)(vp + off);
  float4 v1 = *(const float4*)(vp + off + 4);
  half8 h;
  h[0] = (_Float16)fmaxf(k0.x + v0.x, 0.f);
  h[1] = (_Float16)fmaxf(k0.y + v0.y, 0.f);
  h[2] = (_Float16)fmaxf(k0.z + v0.z, 0.f);
  h[3] = (_Float16)fmaxf(k0.w + v0.w, 0.f);
  h[4] = (_Float16)fmaxf(k1.x + v1.x, 0.f);
  h[5] = (_Float16)fmaxf(k1.y + v1.y, 0.f);
  h[6] = (_Float16)fmaxf(k1.z + v1.z, 0.f);
  h[7] = (_Float16)fmaxf(k1.w + v1.w, 0.f);
  return h;
}

template <bool FUSE_EMBED>
__global__ __launch_bounds__(256) void gemm_mfma_kernel(
    const __half* __restrict__ A, const int* __restrict__ feats,
    const float* __restrict__ ke, const float* __restrict__ ve,
    const __half* __restrict__ Wt, __half* __restrict__ F, int N) {
  int w = threadIdx.x >> 6;
  int lane = threadIdx.x & 63;
  int r = lane & 15, g = lane >> 4;
  int row0 = blockIdx.x * 64 + w * 16;
  if (row0 >= N) return;
  int arow = row0 + r;
  if (arow >= N) arow = N - 1;        // clamp (stores are guarded)
  half8 a0, a1, a2, a3;
  if (FUSE_EMBED) {
    int f0 = feats[2 * arow], f1 = feats[2 * arow + 1];
    const float* kp = ke + (size_t)f0 * HID;
    const float* vp = ve + (size_t)f1 * HID;
    a0 = embed8(kp, vp, g * 8);
    a1 = embed8(kp, vp, 32 + g * 8);
    a2 = embed8(kp, vp, 64 + g * 8);
    a3 = embed8(kp, vp, 96 + g * 8);
  } else {
    const half8* Ap = (const half8*)(A + (size_t)arow * HID + g * 8);
    a0 = Ap[0];
    a1 = Ap[4];
    a2 = Ap[8];
    a3 = Ap[12];
  }
#pragma unroll
  for (int ct = 0; ct < 8; ++ct) {
    const half8* Bp = (const half8*)(Wt + (size_t)(ct * 16 + r) * HID + g * 8);
    half8 b0 = Bp[0], b1 = Bp[4], b2 = Bp[8], b3 = Bp[12];
    floatx4 c = {0.f, 0.f, 0.f, 0.f};
    c = __builtin_amdgcn_mfma_f32_16x16x32_f16(a0, b0, c, 0, 0, 0);
    c = __builtin_amdgcn_mfma_f32_16x16x32_f16(a1, b1, c, 0, 0, 0);
    c = __builtin_amdgcn_mfma_f32_16x16x32_f16(a2, b2, c, 0, 0, 0);
    c = __builtin_amdgcn_mfma_f32_16x16x32_f16(a3, b3, c, 0, 0, 0);
    int col = ct * 16 + r;
#pragma unroll
    for (int reg = 0; reg < 4; ++reg) {
      int row = row0 + g * 4 + reg;
      if (row < N) F[(size_t)row * HID + col] = __float2half(c[reg]);
    }
  }
}

// ---------------- GATv2 layer (32-lane groups, 8-wide, depth-1 prefetch) ----
// 32-lane group = 1 node (2/wave, 8/block); lane holds dims 4q..4q+3;
// 8 edges/iter (CSR padded to 8); NEXT octet's 8 gathers issue as fp16 raws
// (16 VGPR) BEFORE the current octet's compute -> 16 gathers in flight while
// keeping the butterfly/logit register set at 8-wide size (~56 VGPR, under
// the 64-VGPR occupancy cliff). One exp per 8 edges; bpermute broadcast.
__device__ __forceinline__ float dot4f(const float4& f, const float4& fd,
                                       const float4& a6, const float4& a4) {
  float t, p;
  t = f.x + fd.x; p = a6.x * t;         p = fmaf(a4.x, fabsf(t), p);
  t = f.y + fd.y; p = fmaf(a6.y, t, p); p = fmaf(a4.y, fabsf(t), p);
  t = f.z + fd.z; p = fmaf(a6.z, t, p); p = fmaf(a4.z, fabsf(t), p);
  t = f.w + fd.w; p = fmaf(a6.w, t, p); p = fmaf(a4.w, fabsf(t), p);
  return p;
}

// main loop body shared by gat_kernel and gat_cls_kernel (no returns inside)
#define GAT_BODY(NODEC, CNT)                                                    \
  int q = threadIdx.x & 31;                                                     \
  int lane = threadIdx.x & 63;                                                  \
  const h4pack* F4h = (const h4pack*)F;                                         \
  float4 fd = h4tof4(F4h[(size_t)(NODEC) * 32 + q]);                            \
  float4 av = ((const float4*)attn)[q];                                         \
  float4 a6, a4;                                                                \
  a6.x = 0.6f * av.x; a6.y = 0.6f * av.y; a6.z = 0.6f * av.z; a6.w = 0.6f * av.w; \
  a4.x = 0.4f * av.x; a4.y = 0.4f * av.y; a4.z = 0.4f * av.z; a4.w = 0.4f * av.w; \
  int ib = (lane & 32) << 2;                                                    \
  bool b1 = (q & 1) != 0;                                                       \
  bool b2 = (q & 2) != 0;                                                       \
  bool b4 = (q & 4) != 0;                                                       \
  int beg = offs[(NODEC)];                                                      \
  int cnt = (CNT);                                                              \
  float l = 0.f;                                                                \
  float4 acc = make_float4(0.f, 0.f, 0.f, 0.f);                                 \
  int nit = (cnt + 7) >> 3;                                                     \
  const int4* qp = (const int4*)(csr + beg);                                    \
  h4pack cr0, cr1, cr2, cr3, cr4, cr5, cr6, cr7;                                \
  if (nit > 0) {                                                                \
    int4 sa = qp[0];                                                            \
    int4 sb = qp[1];                                                            \
    cr0 = F4h[(size_t)sa.x * 32 + q];                                           \
    cr1 = F4h[(size_t)sa.y * 32 + q];                                           \
    cr2 = F4h[(size_t)sa.z * 32 + q];                                           \
    cr3 = F4h[(size_t)sa.w * 32 + q];                                           \
    cr4 = F4h[(size_t)sb.x * 32 + q];                                           \
    cr5 = F4h[(size_t)sb.y * 32 + q];                                           \
    cr6 = F4h[(size_t)sb.z * 32 + q];                                           \
    cr7 = F4h[(size_t)sb.w * 32 + q];                                           \
  }                                                                             \
  for (int it = 0; it < nit; ++it) {                                            \
    bool more = (it + 1 < nit);                                                 \
    h4pack nr0, nr1, nr2, nr3, nr4, nr5, nr6, nr7;                              \
    if (more) {                       /* prefetch next octet (fp16 raws) */     \
      int4 sa = qp[2 * it + 2];                                                 \
      int4 sb = qp[2 * it + 3];                                                 \
      nr0 = F4h[(size_t)sa.x * 32 + q];                                         \
      nr1 = F4h[(size_t)sa.y * 32 + q];                                         \
      nr2 = F4h[(size_t)sa.z * 32 + q];                                         \
      nr3 = F4h[(size_t)sa.w * 32 + q];                                         \
      nr4 = F4h[(size_t)sb.x * 32 + q];                                         \
      nr5 = F4h[(size_t)sb.y * 32 + q];                                         \
      nr6 = F4h[(size_t)sb.z * 32 + q];                                         \
      nr7 = F4h[(size_t)sb.w * 32 + q];                                         \
    }                                                                           \
    float4 fa0 = h4tof4(cr0);                                                   \
    float4 fa1 = h4tof4(cr1);                                                   \
    float4 fa2 = h4tof4(cr2);                                                   \
    float4 fa3 = h4tof4(cr3);                                                   \
    float4 fb0 = h4tof4(cr4);                                                   \
    float4 fb1 = h4tof4(cr5);                                                   \
    float4 fb2 = h4tof4(cr6);                                                   \
    float4 fb3 = h4tof4(cr7);                                                   \
    int rem = cnt - 8 * it;                                                     \
    float p0 = dot4f(fa0, fd, a6, a4);                                          \
    float p1 = (1 < rem) ? dot4f(fa1, fd, a6, a4) : -INFINITY;                  \
    float p2 = (2 < rem) ? dot4f(fa2, fd, a6, a4) : -INFINITY;                  \
    float p3 = (3 < rem) ? dot4f(fa3, fd, a6, a4) : -INFINITY;                  \
    float p4 = (4 < rem) ? dot4f(fb0, fd, a6, a4) : -INFINITY;                  \
    float p5 = (5 < rem) ? dot4f(fb1, fd, a6, a4) : -INFINITY;                  \
    float p6 = (6 < rem) ? dot4f(fb2, fd, a6, a4) : -INFINITY;                  \
    float p7 = (7 < rem) ? dot4f(fb3, fd, a6, a4) : -INFINITY;                  \
    float u0 = p0 + __shfl_xor(p0, 1, 64);                                      \
    float u1 = p1 + __shfl_xor(p1, 1, 64);                                      \
    float u2 = p2 + __shfl_xor(p2, 1, 64);                                      \
    float u3 = p3 + __shfl_xor(p3, 1, 64);                                      \
    float u4 = p4 + __shfl_xor(p4, 1, 64);                                      \
    float u5 = p5 + __shfl_xor(p5, 1, 64);                                      \
    float u6 = p6 + __shfl_xor(p6, 1, 64);                                      \
    float u7 = p7 + __shfl_xor(p7, 1, 64);                                      \
    float c0 = b1 ? u1 : u0;                                                    \
    float c1 = b1 ? u3 : u2;                                                    \
    float c2 = b1 ? u5 : u4;                                                    \
    float c3 = b1 ? u7 : u6;                                                    \
    float d0 = c0 + __shfl_xor(c0, 2, 64);                                      \
    float d1 = c1 + __shfl_xor(c1, 2, 64);                                      \
    float d2 = c2 + __shfl_xor(c2, 2, 64);                                      \
    float d3 = c3 + __shfl_xor(c3, 2, 64);                                      \
    float w0 = b2 ? d1 : d0;                                                    \
    float w1 = b2 ? d3 : d2;                                                    \
    float x0 = w0 + __shfl_xor(w0, 4, 64);                                      \
    float x1 = w1 + __shfl_xor(w1, 4, 64);                                      \
    float r = b4 ? x1 : x0;                                                     \
    r += __shfl_xor(r, 8, 64);                                                  \
    r += __shfl_xor(r, 16, 64);                                                 \
    float ex = __expf(r);                                                       \
    int exi = __float_as_int(ex);                                               \
    float e0 = __int_as_float(__builtin_amdgcn_ds_bpermute(ib +  0, exi));      \
    float e1 = __int_as_float(__builtin_amdgcn_ds_bpermute(ib +  4, exi));      \
    float e2 = __int_as_float(__builtin_amdgcn_ds_bpermute(ib +  8, exi));      \
    float e3 = __int_as_float(__builtin_amdgcn_ds_bpermute(ib + 12, exi));      \
    float e4 = __int_as_float(__builtin_amdgcn_ds_bpermute(ib + 16, exi));      \
    float e5 = __int_as_float(__builtin_amdgcn_ds_bpermute(ib + 20, exi));      \
    float e6 = __int_as_float(__builtin_amdgcn_ds_bpermute(ib + 24, exi));      \
    float e7 = __int_as_float(__builtin_amdgcn_ds_bpermute(ib + 28, exi));      \
    l += ((e0 + e1) + (e2 + e3)) + ((e4 + e5) + (e6 + e7));                     \
    acc.x = fmaf(e0, fa0.x, acc.x); acc.x = fmaf(e1, fa1.x, acc.x);             \
    acc.x = fmaf(e2, fa2.x, acc.x); acc.x = fmaf(e3, fa3.x, acc.x);             \
    acc.x = fmaf(e4, fb0.x, acc.x); acc.x = fmaf(e5, fb1.x, acc.x);             \
    acc.x = fmaf(e6, fb2.x, acc.x); acc.x = fmaf(e7, fb3.x, acc.x);             \
    acc.y = fmaf(e0, fa0.y, acc.y); acc.y = fmaf(e1, fa1.y, acc.y);             \
    acc.y = fmaf(e2, fa2.y, acc.y); acc.y = fmaf(e3, fa3.y, acc.y);             \
    acc.y = fmaf(e4, fb0.y, acc.y); acc.y = fmaf(e5, fb1.y, acc.y);             \
    acc.y = fmaf(e6, fb2.y, acc.y); acc.y = fmaf(e7, fb3.y, acc.y);             \
    acc.z = fmaf(e0, fa0.z, acc.z); acc.z = fmaf(e1, fa1.z, acc.z);             \
    acc.z = fmaf(e2, fa2.z, acc.z); acc.z = fmaf(e3, fa3.z, acc.z);             \
    acc.z = fmaf(e4, fb0.z, acc.z); acc.z = fmaf(e5, fb1.z, acc.z);             \
    acc.z = fmaf(e6, fb2.z, acc.z); acc.z = fmaf(e7, fb3.z, acc.z);             \
    acc.w = fmaf(e0, fa0.w, acc.w); acc.w = fmaf(e1, fa1.w, acc.w);             \
    acc.w = fmaf(e2, fa2.w, acc.w); acc.w = fmaf(e3, fa3.w, acc.w);             \
    acc.w = fmaf(e4, fb0.w, acc.w); acc.w = fmaf(e5, fb1.w, acc.w);             \
    acc.w = fmaf(e6, fb2.w, acc.w); acc.w = fmaf(e7, fb3.w, acc.w);             \
    if (more) {                                                                 \
      cr0 = nr0; cr1 = nr1; cr2 = nr2; cr3 = nr3;                               \
      cr4 = nr4; cr5 = nr5; cr6 = nr6; cr7 = nr7;                               \
    }                                                                           \
  }                                                                             \
  float inv = (l > 0.f) ? 1.f / l : 0.f;                                        \
  acc.x *= inv; acc.y *= inv; acc.z *= inv; acc.w *= inv;

__global__ __launch_bounds__(256) void gat_kernel(
    const __half* __restrict__ F, const int* __restrict__ offs,
    const int* __restrict__ counts, const int* __restrict__ csr,
    const float* __restrict__ attn, __half* __restrict__ Hout, int N) {
  int node = blockIdx.x * 8 + (threadIdx.x >> 5);
  if (node >= N) return;
  GAT_BODY(node, counts[node])
  ((h4pack*)Hout)[(size_t)node * 32 + q] = f4toh4(acc);
}

// gat layer 2 + classify fused via LDS (padded stride kills bank conflicts).
// No early returns: invalid nodes clamp to N-1 with cnt=0.
#define SH_STRIDE 132   // 132 % 32 == 4 -> 8 rows hit 8 distinct banks
__global__ __launch_bounds__(256) void gat_cls_kernel(
    const __half* __restrict__ F, const int* __restrict__ offs,
    const int* __restrict__ counts, const int* __restrict__ csr,
    const float* __restrict__ attn, const float* __restrict__ clsw,
    float* __restrict__ out, int N) {
  __shared__ float sW[HID * 16];           // 8 KB
  __shared__ float sH[8 * SH_STRIDE];      // ~4.1 KB, padded rows
  for (int i = threadIdx.x; i < HID * 16; i += 256) sW[i] = clsw[i];
  int node = blockIdx.x * 8 + (threadIdx.x >> 5);
  bool valid = node < N;
  int nodec = valid ? node : N - 1;
  GAT_BODY(nodec, valid ? counts[nodec] : 0)
  int g = threadIdx.x >> 5;
  float* shrow = sH + g * SH_STRIDE + q * 4;
  shrow[0] = acc.x;
  shrow[1] = acc.y;
  shrow[2] = acc.z;
  shrow[3] = acc.w;
  __syncthreads();
  if (threadIdx.x < 128) {
    int ns = threadIdx.x >> 4;     // node slot 0..7
    int c = threadIdx.x & 15;      // output col
    const float* hrow = sH + ns * SH_STRIDE;
    float y = 0.f;
#pragma unroll 8
    for (int k = 0; k < HID; ++k) y = fmaf(hrow[k], sW[k * 16 + c], y);
    int onode = blockIdx.x * 8 + ns;
    if (onode < N) out[(size_t)onode * 16 + c] = y;
  }
}

// ---------------------------------------------------------------------------
extern "C" void kernel_launch(void* const* d_in, const int* in_sizes, int n_in,
                              void* d_out, int out_size, void* d_ws, size_t ws_size,
                              hipStream_t stream) {
  const int* feats     = (const int*)d_in[0];
  const int* src       = (const int*)d_in[1];
  const int* dst       = (const int*)d_in[2];
  const float* key_emb = (const float*)d_in[3];
  const float* val_emb = (const float*)d_in[4];
  const float* W1      = (const float*)d_in[5];
  const float* attn1   = (const float*)d_in[6];
  const float* W2      = (const float*)d_in[7];
  const float* attn2   = (const float*)d_in[8];
  const float* cls_w   = (const float*)d_in[9];

  int N = in_sizes[0] / 2;
  int E = in_sizes[1];
  int NB = (N + 255) / 256;

  // 16B-aligned workspace layout
  int Np = (N + 3) & ~3;
  int Ep = (E + 3) & ~3;
  char* ws = (char*)d_ws;
  __half* fbuf  = (__half*)ws;                            // Np*128 fp16
  __half* hbuf  = (__half*)(ws + (size_t)Np * HID * 2);   // Np*128 fp16
  __half* Wt1   = (__half*)(ws + (size_t)Np * HID * 4);   // 128*128 fp16
  __half* Wt2   = Wt1 + HID * HID;                        // 128*128 fp16
  int* counts   = (int*)(Wt2 + HID * HID);                // Np
  int* offs     = counts + Np;                            // Np+4
  int* rank     = offs + Np + 4;                          // Ep
  int* csr      = rank + Ep;                              // Ep + 8*Np (8-padded)
  int* partials = csr + Ep + 8 * (size_t)Np;              // 256
  int* bases    = partials + 256;                         // 256

  zero_kernel<<<(Np / 4 + 255) / 256, 256, 0, stream>>>((int4*)counts, Np / 4);

  hist_kernel<<<(E + 255) / 256, 256, 0, stream>>>(dst, counts, rank, E);
  partial_kernel<<<NB, 256, 0, stream>>>(counts, partials, N);
  scan2_kernel<<<1, 256, 0, stream>>>(partials, bases, NB);
  offs_kernel<<<NB, 256, 0, stream>>>(counts, bases, offs, csr, N);
  scatter_kernel<<<(E + 255) / 256, 256, 0, stream>>>(src, dst, offs, rank, csr, E);
  wprep2_kernel<<<128, 256, 0, stream>>>(W1, W2, Wt1, Wt2);

  int gblocks = (N + 63) / 64;
  int gatblocks = (N + 7) / 8;
  // layer 1 (embed fused into gemm1's A-fragment load)
  gemm_mfma_kernel<true><<<gblocks, 256, 0, stream>>>(
      nullptr, feats, key_emb, val_emb, Wt1, fbuf, N);
  gat_kernel<<<gatblocks, 256, 0, stream>>>(
      fbuf, offs, counts, csr, attn1, hbuf, N);
  // layer 2 (+ classify fused via LDS)
  gemm_mfma_kernel<false><<<gblocks, 256, 0, stream>>>(
      hbuf, nullptr, nullptr, nullptr, Wt2, fbuf, N);
  gat_cls_kernel<<<gatblocks, 256, 0, stream>>>(
      fbuf, offs, counts, csr, attn2, cls_w, (float*)d_out, N);
}

// Round 25
// 201.760 us; speedup vs baseline: 1.1054x; 1.1054x over previous
//
#include <hip/hip_runtime.h>
#include <hip/hip_fp16.h>
#include <math.h>

#define HID 128

typedef _Float16 half8 __attribute__((ext_vector_type(8)));
typedef float floatx4 __attribute__((ext_vector_type(4)));

// 8-byte packed 4x fp16
struct h4pack { __half2 a, b; };

__device__ __forceinline__ float4 h4tof4(h4pack h) {
  float2 lo = __half22float2(h.a);
  float2 hi = __half22float2(h.b);
  return make_float4(lo.x, lo.y, hi.x, hi.y);
}

__device__ __forceinline__ h4pack f4toh4(float4 v) {
  h4pack h;
  h.a = __floats2half2_rn(v.x, v.y);
  h.b = __floats2half2_rn(v.z, v.w);
  return h;
}

// ---------------- zero workspace --------------------------------------------
__global__ __launch_bounds__(256) void zero_kernel(int4* __restrict__ p, int n4) {
  int i = blockIdx.x * 256 + threadIdx.x;
  if (i < n4) p[i] = make_int4(0, 0, 0, 0);
}

// ---------------- CSR build (padded to 8-edge octets) ------------------------
__global__ __launch_bounds__(256) void hist_kernel(
    const int* __restrict__ dst, int* __restrict__ counts,
    int* __restrict__ rank, int E) {
  int e = blockIdx.x * 256 + threadIdx.x;
  if (e < E) rank[e] = atomicAdd(&counts[dst[e]], 1);
}

__global__ __launch_bounds__(256) void partial_kernel(
    const int* __restrict__ counts, int* __restrict__ partials, int N) {
  __shared__ int s[256];
  int idx = blockIdx.x * 256 + threadIdx.x;
  int c = (idx < N) ? counts[idx] : 0;
  s[threadIdx.x] = (idx < N) ? ((c + 7) & ~7) : 0;
  __syncthreads();
  for (int o = 128; o > 0; o >>= 1) {
    if (threadIdx.x < o) s[threadIdx.x] += s[threadIdx.x + o];
    __syncthreads();
  }
  if (threadIdx.x == 0) partials[blockIdx.x] = s[0];
}

__global__ __launch_bounds__(256) void scan2_kernel(
    const int* __restrict__ partials, int* __restrict__ bases, int NB) {
  __shared__ int s[256];
  int t = threadIdx.x;
  int v0 = (t < NB) ? partials[t] : 0;
  s[t] = v0;
  __syncthreads();
  for (int o = 1; o < 256; o <<= 1) {
    int v = (t >= o) ? s[t - o] : 0;
    __syncthreads();
    s[t] += v;
    __syncthreads();
  }
  bases[t] = s[t] - v0;   // exclusive
}

// offs + pad-fill (pads -> node 0; nulled in gat via true-count masking)
__global__ __launch_bounds__(256) void offs_kernel(
    const int* __restrict__ counts, const int* __restrict__ bases,
    int* __restrict__ offs, int* __restrict__ csr, int N) {
  __shared__ int s[256];
  int t = threadIdx.x;
  int idx = blockIdx.x * 256 + t;
  int deg = (idx < N) ? counts[idx] : 0;
  int c = (idx < N) ? ((deg + 7) & ~7) : 0;
  s[t] = c;
  __syncthreads();
  for (int o = 1; o < 256; o <<= 1) {
    int v = (t >= o) ? s[t - o] : 0;
    __syncthreads();
    s[t] += v;
    __syncthreads();
  }
  int base = bases[blockIdx.x];
  if (idx < N) {
    int o = base + s[t] - c;
    offs[idx] = o;
    for (int k = deg; k < c; ++k) csr[o + k] = 0;
  }
  if (idx == N - 1) offs[N] = base + s[t];
}

__global__ __launch_bounds__(256) void scatter_kernel(
    const int* __restrict__ src, const int* __restrict__ dst,
    const int* __restrict__ offs, const int* __restrict__ rank,
    int* __restrict__ csr, int E) {
  int e = blockIdx.x * 256 + threadIdx.x;
  if (e >= E) return;
  csr[offs[dst[e]] + rank[e]] = src[e];
}

// ---------------- W prep: both layers in one dispatch -----------------------
__global__ __launch_bounds__(256) void wprep2_kernel(
    const float* __restrict__ W1, const float* __restrict__ W2,
    __half* __restrict__ Wt1, __half* __restrict__ Wt2) {
  int b = blockIdx.x;
  const float* W = (b < 64) ? W1 : W2;
  __half* Wt = (b < 64) ? Wt1 : Wt2;
  int t = (b & 63) * 256 + threadIdx.x;   // 0..16383
  int k = t >> 7, c = t & 127;
  Wt[(size_t)c * HID + k] = __float2half(W[t]);
}

// ---------------- GEMM via MFMA: F[N,128](fp16) = A @ W ---------------------
__device__ __forceinline__ half8 embed8(const float* __restrict__ kp,
                                        const float* __restrict__ vp, int off) {
  float4 k0 = *(const float4*)(kp + off);
  float4 k1 = *(const float4*)(kp + off + 4);
  float4 v0 = *(const float4*)(vp + off);
  float4 v1 = *(const float4*)(vp + off + 4);
  half8 h;
  h[0] = (_Float16)fmaxf(k0.x + v0.x, 0.f);
  h[1] = (_Float16)fmaxf(k0.y + v0.y, 0.f);
  h[2] = (_Float16)fmaxf(k0.z + v0.z, 0.f);
  h[3] = (_Float16)fmaxf(k0.w + v0.w, 0.f);
  h[4] = (_Float16)fmaxf(k1.x + v1.x, 0.f);
  h[5] = (_Float16)fmaxf(k1.y + v1.y, 0.f);
  h[6] = (_Float16)fmaxf(k1.z + v1.z, 0.f);
  h[7] = (_Float16)fmaxf(k1.w + v1.w, 0.f);
  return h;
}

template <bool FUSE_EMBED>
__global__ __launch_bounds__(256) void gemm_mfma_kernel(
    const __half* __restrict__ A, const int* __restrict__ feats,
    const float* __restrict__ ke, const float* __restrict__ ve,
    const __half* __restrict__ Wt, __half* __restrict__ F, int N) {
  int w = threadIdx.x >> 6;
  int lane = threadIdx.x & 63;
  int r = lane & 15, g = lane >> 4;
  int row0 = blockIdx.x * 64 + w * 16;
  if (row0 >= N) return;
  int arow = row0 + r;
  if (arow >= N) arow = N - 1;        // clamp (stores are guarded)
  half8 a0, a1, a2, a3;
  if (FUSE_EMBED) {
    int f0 = feats[2 * arow], f1 = feats[2 * arow + 1];
    const float* kp = ke + (size_t)f0 * HID;
    const float* vp = ve + (size_t)f1 * HID;
    a0 = embed8(kp, vp, g * 8);
    a1 = embed8(kp, vp, 32 + g * 8);
    a2 = embed8(kp, vp, 64 + g * 8);
    a3 = embed8(kp, vp, 96 + g * 8);
  } else {
    const half8* Ap = (const half8*)(A + (size_t)arow * HID + g * 8);
    a0 = Ap[0];
    a1 = Ap[4];
    a2 = Ap[8];
    a3 = Ap[12];
  }
#pragma unroll
  for (int ct = 0; ct < 8; ++ct) {
    const half8* Bp = (const half8*)(Wt + (size_t)(ct * 16 + r) * HID + g * 8);
    half8 b0 = Bp[0], b1 = Bp[4], b2 = Bp[8], b3 = Bp[12];
    floatx4 c = {0.f, 0.f, 0.f, 0.f};
    c = __builtin_amdgcn_mfma_f32_16x16x32_f16(a0, b0, c, 0, 0, 0);
    c = __builtin_amdgcn_mfma_f32_16x16x32_f16(a1, b1, c, 0, 0, 0);
    c = __builtin_amdgcn_mfma_f32_16x16x32_f16(a2, b2, c, 0, 0, 0);
    c = __builtin_amdgcn_mfma_f32_16x16x32_f16(a3, b3, c, 0, 0, 0);
    int col = ct * 16 + r;
#pragma unroll
    for (int reg = 0; reg < 4; ++reg) {
      int row = row0 + g * 4 + reg;
      if (row < N) F[(size_t)row * HID + col] = __float2half(c[reg]);
    }
  }
}

// ---------------- GATv2 layer (32-lane groups, 8-wide, no-max) --------------
__device__ __forceinline__ float dot4f(const float4& f, const float4& fd,
                                       const float4& a6, const float4& a4) {
  float t, p;
  t = f.x + fd.x; p = a6.x * t;         p = fmaf(a4.x, fabsf(t), p);
  t = f.y + fd.y; p = fmaf(a6.y, t, p); p = fmaf(a4.y, fabsf(t), p);
  t = f.z + fd.z; p = fmaf(a6.z, t, p); p = fmaf(a4.z, fabsf(t), p);
  t = f.w + fd.w; p = fmaf(a6.w, t, p); p = fmaf(a4.w, fabsf(t), p);
  return p;
}

// main loop body shared by gat_kernel and gat_cls_kernel (no returns inside)
#define GAT_BODY(NODEC, CNT)                                                    \
  int q = threadIdx.x & 31;                                                     \
  int lane = threadIdx.x & 63;                                                  \
  const h4pack* F4h = (const h4pack*)F;                                         \
  float4 fd = h4tof4(F4h[(size_t)(NODEC) * 32 + q]);                            \
  float4 av = ((const float4*)attn)[q];                                         \
  float4 a6, a4;                                                                \
  a6.x = 0.6f * av.x; a6.y = 0.6f * av.y; a6.z = 0.6f * av.z; a6.w = 0.6f * av.w; \
  a4.x = 0.4f * av.x; a4.y = 0.4f * av.y; a4.z = 0.4f * av.z; a4.w = 0.4f * av.w; \
  int ib = (lane & 32) << 2;                                                    \
  bool b1 = (q & 1) != 0;                                                       \
  bool b2 = (q & 2) != 0;                                                       \
  bool b4 = (q & 4) != 0;                                                       \
  int beg = offs[(NODEC)];                                                      \
  int cnt = (CNT);                                                              \
  float l = 0.f;                                                                \
  float4 acc = make_float4(0.f, 0.f, 0.f, 0.f);                                 \
  int nit = (cnt + 7) >> 3;                                                     \
  const int* cp = csr + beg;                                                    \
  for (int it = 0; it < nit; ++it) {                                            \
    const int4* qp = (const int4*)(cp + 8 * it);                                \
    int4 sa = qp[0];                                                            \
    int4 sb = qp[1];                                                            \
    float4 fa0 = h4tof4(F4h[(size_t)sa.x * 32 + q]);                            \
    float4 fa1 = h4tof4(F4h[(size_t)sa.y * 32 + q]);                            \
    float4 fa2 = h4tof4(F4h[(size_t)sa.z * 32 + q]);                            \
    float4 fa3 = h4tof4(F4h[(size_t)sa.w * 32 + q]);                            \
    float4 fb0 = h4tof4(F4h[(size_t)sb.x * 32 + q]);                            \
    float4 fb1 = h4tof4(F4h[(size_t)sb.y * 32 + q]);                            \
    float4 fb2 = h4tof4(F4h[(size_t)sb.z * 32 + q]);                            \
    float4 fb3 = h4tof4(F4h[(size_t)sb.w * 32 + q]);                            \
    int rem = cnt - 8 * it;                                                     \
    float p0 = dot4f(fa0, fd, a6, a4);                                          \
    float p1 = (1 < rem) ? dot4f(fa1, fd, a6, a4) : -INFINITY;                  \
    float p2 = (2 < rem) ? dot4f(fa2, fd, a6, a4) : -INFINITY;                  \
    float p3 = (3 < rem) ? dot4f(fa3, fd, a6, a4) : -INFINITY;                  \
    float p4 = (4 < rem) ? dot4f(fb0, fd, a6, a4) : -INFINITY;                  \
    float p5 = (5 < rem) ? dot4f(fb1, fd, a6, a4) : -INFINITY;                  \
    float p6 = (6 < rem) ? dot4f(fb2, fd, a6, a4) : -INFINITY;                  \
    float p7 = (7 < rem) ? dot4f(fb3, fd, a6, a4) : -INFINITY;                  \
    float u0 = p0 + __shfl_xor(p0, 1, 64);                                      \
    float u1 = p1 + __shfl_xor(p1, 1, 64);                                      \
    float u2 = p2 + __shfl_xor(p2, 1, 64);                                      \
    float u3 = p3 + __shfl_xor(p3, 1, 64);                                      \
    float u4 = p4 + __shfl_xor(p4, 1, 64);                                      \
    float u5 = p5 + __shfl_xor(p5, 1, 64);                                      \
    float u6 = p6 + __shfl_xor(p6, 1, 64);                                      \
    float u7 = p7 + __shfl_xor(p7, 1, 64);                                      \
    float c0 = b1 ? u1 : u0;                                                    \
    float c1 = b1 ? u3 : u2;                                                    \
    float c2 = b1 ? u5 : u4;                                                    \
    float c3 = b1 ? u7 : u6;                                                    \
    float d0 = c0 + __shfl_xor(c0, 2, 64);                                      \
    float d1 = c1 + __shfl_xor(c1, 2, 64);                                      \
    float d2 = c2 + __shfl_xor(c2, 2, 64);                                      \
    float d3 = c3 + __shfl_xor(c3, 2, 64);                                      \
    float w0 = b2 ? d1 : d0;                                                    \
    float w1 = b2 ? d3 : d2;                                                    \
    float x0 = w0 + __shfl_xor(w0, 4, 64);                                      \
    float x1 = w1 + __shfl_xor(w1, 4, 64);                                      \
    float r = b4 ? x1 : x0;                                                     \
    r += __shfl_xor(r, 8, 64);                                                  \
    r += __shfl_xor(r, 16, 64);                                                 \
    float ex = __expf(r);                                                       \
    int exi = __float_as_int(ex);                                               \
    float e0 = __int_as_float(__builtin_amdgcn_ds_bpermute(ib +  0, exi));      \
    float e1 = __int_as_float(__builtin_amdgcn_ds_bpermute(ib +  4, exi));      \
    float e2 = __int_as_float(__builtin_amdgcn_ds_bpermute(ib +  8, exi));      \
    float e3 = __int_as_float(__builtin_amdgcn_ds_bpermute(ib + 12, exi));      \
    float e4 = __int_as_float(__builtin_amdgcn_ds_bpermute(ib + 16, exi));      \
    float e5 = __int_as_float(__builtin_amdgcn_ds_bpermute(ib + 20, exi));      \
    float e6 = __int_as_float(__builtin_amdgcn_ds_bpermute(ib + 24, exi));      \
    float e7 = __int_as_float(__builtin_amdgcn_ds_bpermute(ib + 28, exi));      \
    l += ((e0 + e1) + (e2 + e3)) + ((e4 + e5) + (e6 + e7));                     \
    acc.x = fmaf(e0, fa0.x, acc.x); acc.x = fmaf(e1, fa1.x, acc.x);             \
    acc.x = fmaf(e2, fa2.x, acc.x); acc.x = fmaf(e3, fa3.x, acc.x);             \
    acc.x = fmaf(e4, fb0.x, acc.x); acc.x = fmaf(e5, fb1.x, acc.x);             \
    acc.x = fmaf(e6, fb2.x, acc.x); acc.x = fmaf(e7, fb3.x, acc.x);             \
    acc.y = fmaf(e0, fa0.y, acc.y); acc.y = fmaf(e1, fa1.y, acc.y);             \
    acc.y = fmaf(e2, fa2.y, acc.y); acc.y = fmaf(e3, fa3.y, acc.y);             \
    acc.y = fmaf(e4, fb0.y, acc.y); acc.y = fmaf(e5, fb1.y, acc.y);             \
    acc.y = fmaf(e6, fb2.y, acc.y); acc.y = fmaf(e7, fb3.y, acc.y);             \
    acc.z = fmaf(e0, fa0.z, acc.z); acc.z = fmaf(e1, fa1.z, acc.z);             \
    acc.z = fmaf(e2, fa2.z, acc.z); acc.z = fmaf(e3, fa3.z, acc.z);             \
    acc.z = fmaf(e4, fb0.z, acc.z); acc.z = fmaf(e5, fb1.z, acc.z);             \
    acc.z = fmaf(e6, fb2.z, acc.z); acc.z = fmaf(e7, fb3.z, acc.z);             \
    acc.w = fmaf(e0, fa0.w, acc.w); acc.w = fmaf(e1, fa1.w, acc.w);             \
    acc.w = fmaf(e2, fa2.w, acc.w); acc.w = fmaf(e3, fa3.w, acc.w);             \
    acc.w = fmaf(e4, fb0.w, acc.w); acc.w = fmaf(e5, fb1.w, acc.w);             \
    acc.w = fmaf(e6, fb2.w, acc.w); acc.w = fmaf(e7, fb3.w, acc.w);             \
  }                                                                             \
  float inv = (l > 0.f) ? 1.f / l : 0.f;                                        \
  acc.x *= inv; acc.y *= inv; acc.z *= inv; acc.w *= inv;

__global__ __launch_bounds__(256) void gat_kernel(
    const __half* __restrict__ F, const int* __restrict__ offs,
    const int* __restrict__ counts, const int* __restrict__ csr,
    const float* __restrict__ attn, __half* __restrict__ Hout, int N) {
  int node = blockIdx.x * 8 + (threadIdx.x >> 5);
  if (node >= N) return;
  GAT_BODY(node, counts[node])
  ((h4pack*)Hout)[(size_t)node * 32 + q] = f4toh4(acc);
}

// gat layer 2 + classify fused via LDS (padded stride kills bank conflicts).
// No early returns: invalid nodes clamp to N-1 with cnt=0.
#define SH_STRIDE 132   // 132 % 32 == 4 -> 8 rows hit 8 distinct banks
__global__ __launch_bounds__(256) void gat_cls_kernel(
    const __half* __restrict__ F, const int* __restrict__ offs,
    const int* __restrict__ counts, const int* __restrict__ csr,
    const float* __restrict__ attn, const float* __restrict__ clsw,
    float* __restrict__ out, int N) {
  __shared__ float sW[HID * 16];           // 8 KB
  __shared__ float sH[8 * SH_STRIDE];      // ~4.1 KB, padded rows
  for (int i = threadIdx.x; i < HID * 16; i += 256) sW[i] = clsw[i];
  int node = blockIdx.x * 8 + (threadIdx.x >> 5);
  bool valid = node < N;
  int nodec = valid ? node : N - 1;
  GAT_BODY(nodec, valid ? counts[nodec] : 0)
  int g = threadIdx.x >> 5;
  float* shrow = sH + g * SH_STRIDE + q * 4;
  shrow[0] = acc.x;
  shrow[1] = acc.y;
  shrow[2] = acc.z;
  shrow[3] = acc.w;
  __syncthreads();
  if (threadIdx.x < 128) {
    int ns = threadIdx.x >> 4;     // node slot 0..7
    int c = threadIdx.x & 15;      // output col
    const float* hrow = sH + ns * SH_STRIDE;
    float y = 0.f;
#pragma unroll 8
    for (int k = 0; k < HID; ++k) y = fmaf(hrow[k], sW[k * 16 + c], y);
    int onode = blockIdx.x * 8 + ns;
    if (onode < N) out[(size_t)onode * 16 + c] = y;
  }
}

// ---------------------------------------------------------------------------
extern "C" void kernel_launch(void* const* d_in, const int* in_sizes, int n_in,
                              void* d_out, int out_size, void* d_ws, size_t ws_size,
                              hipStream_t stream) {
  const int* feats     = (const int*)d_in[0];
  const int* src       = (const int*)d_in[1];
  const int* dst       = (const int*)d_in[2];
  const float* key_emb = (const float*)d_in[3];
  const float* val_emb = (const float*)d_in[4];
  const float* W1      = (const float*)d_in[5];
  const float* attn1   = (const float*)d_in[6];
  const float* W2      = (const float*)d_in[7];
  const float* attn2   = (const float*)d_in[8];
  const float* cls_w   = (const float*)d_in[9];

  int N = in_sizes[0] / 2;
  int E = in_sizes[1];
  int NB = (N + 255) / 256;

  // 16B-aligned workspace layout
  int Np = (N + 3) & ~3;
  int Ep = (E + 3) & ~3;
  char* ws = (char*)d_ws;
  __half* fbuf  = (__half*)ws;                            // Np*128 fp16
  __half* hbuf  = (__half*)(ws + (size_t)Np * HID * 2);   // Np*128 fp16
  __half* Wt1   = (__half*)(ws + (size_t)Np * HID * 4);   // 128*128 fp16
  __half* Wt2   = Wt1 + HID * HID;                        // 128*128 fp16
  int* counts   = (int*)(Wt2 + HID * HID);                // Np
  int* offs     = counts + Np;                            // Np+4
  int* rank     = offs + Np + 4;                          // Ep
  int* csr      = rank + Ep;                              // Ep + 8*Np (8-padded)
  int* partials = csr + Ep + 8 * (size_t)Np;              // 256
  int* bases    = partials + 256;                         // 256

  zero_kernel<<<(Np / 4 + 255) / 256, 256, 0, stream>>>((int4*)counts, Np / 4);

  hist_kernel<<<(E + 255) / 256, 256, 0, stream>>>(dst, counts, rank, E);
  partial_kernel<<<NB, 256, 0, stream>>>(counts, partials, N);
  scan2_kernel<<<1, 256, 0, stream>>>(partials, bases, NB);
  offs_kernel<<<NB, 256, 0, stream>>>(counts, bases, offs, csr, N);
  scatter_kernel<<<(E + 255) / 256, 256, 0, stream>>>(src, dst, offs, rank, csr, E);
  wprep2_kernel<<<128, 256, 0, stream>>>(W1, W2, Wt1, Wt2);

  int gblocks = (N + 63) / 64;
  int gatblocks = (N + 7) / 8;
  // layer 1 (embed fused into gemm1's A-fragment load)
  gemm_mfma_kernel<true><<<gblocks, 256, 0, stream>>>(
      nullptr, feats, key_emb, val_emb, Wt1, fbuf, N);
  gat_kernel<<<gatblocks, 256, 0, stream>>>(
      fbuf, offs, counts, csr, attn1, hbuf, N);
  // layer 2 (+ classify fused via LDS)
  gemm_mfma_kernel<false><<<gblocks, 256, 0, stream>>>(
      hbuf, nullptr, nullptr, nullptr, Wt2, fbuf, N);
  gat_cls_kernel<<<gatblocks, 256, 0, stream>>>(
      fbuf, offs, counts, csr, attn2, cls_w, (float*)d_out, N);
}